// Round 6
// baseline (380.955 us; speedup 1.0000x reference)
//
#include <hip/hip_runtime.h>
#include <math.h>

#define N_NODES 100000
#define N_EDGES 3200000
#define E_TOT   (N_EDGES + N_NODES)
#define F_IN    128
#define H1      16
#define H2      8
#define NEG     0.2f
#define NBUCKET ((N_NODES + 255) >> 8)             // 391 buckets of 256 nodes
#define NCHUNK  512
#define CE      ((N_EDGES + NCHUNK - 1) / NCHUNK)  // 6250 edges per chunk
#define UA      8                                  // gather batch depth

typedef _Float16 half4v __attribute__((ext_vector_type(4)));

// ---- kernel 1: h1(fp16) = x @ W1 ; e1s = h1·a1s ; e1d = h1·a1d ----
__global__ __launch_bounds__(256) void k1_xw(
        const float* __restrict__ x, const float* __restrict__ W1,
        const float* __restrict__ a1s, const float* __restrict__ a1d,
        _Float16* __restrict__ h1h, float* __restrict__ e1s, float* __restrict__ e1d) {
    __shared__ float w1s[F_IN * H1];     // 8 KB
    __shared__ float xs[16 * 132];       // padded stride 132 -> conflict-free
    __shared__ float a1ss[H1], a1ds[H1];
    const int tid = threadIdx.x;
    for (int i = tid; i < F_IN * H1; i += 256) w1s[i] = W1[i];
    if (tid < H1) { a1ss[tid] = a1s[tid]; a1ds[tid] = a1d[tid]; }
    const int rowbase = blockIdx.x * 16;
    #pragma unroll
    for (int i = 0; i < 2; i++) {
        int q = tid + i * 256;
        int r = q >> 5, c = q & 31;
        float4 v = *(const float4*)(x + (size_t)(rowbase + r) * F_IN + c * 4);
        *(float4*)(xs + r * 132 + c * 4) = v;
    }
    __syncthreads();
    const int g = tid >> 4, j = tid & 15;
    const float* xrow = xs + g * 132;
    float acc = 0.f;
    #pragma unroll 8
    for (int k = 0; k < F_IN; k++) acc += xrow[k] * w1s[k * H1 + j];
    const int row = rowbase + g;
    h1h[(size_t)row * H1 + j] = (_Float16)acc;
    float ps = acc * a1ss[j];
    float pd = acc * a1ds[j];
    #pragma unroll
    for (int m = 8; m >= 1; m >>= 1) {
        ps += __shfl_xor(ps, m, 16);
        pd += __shfl_xor(pd, m, 16);
    }
    if (j == 0) { e1s[row] = ps; e1d[row] = pd; }
}

// ---- counting-sort CSR build (no global atomics) ----

__global__ __launch_bounds__(256) void k_count(const int2* __restrict__ ei,
                                               int* __restrict__ counts) {
    __shared__ int hist[NBUCKET];
    for (int i = threadIdx.x; i < NBUCKET; i += 256) hist[i] = 0;
    __syncthreads();
    const int b = blockIdx.x;
    const int beg = b * CE, end = min(N_EDGES, beg + CE);
    for (int e = beg + threadIdx.x; e < end; e += 256)
        atomicAdd(&hist[__builtin_nontemporal_load(&ei[e].y) >> 8], 1);
    __syncthreads();
    for (int i = threadIdx.x; i < NBUCKET; i += 256)
        counts[i * NCHUNK + b] = hist[i];
}

__global__ __launch_bounds__(512) void k_scanA(int* __restrict__ counts,
                                               int* __restrict__ btot) {
    __shared__ int lds[NCHUNK];
    const int k = blockIdx.x, t = threadIdx.x;
    int v = counts[k * NCHUNK + t];
    lds[t] = v;
    __syncthreads();
    for (int off = 1; off < NCHUNK; off <<= 1) {
        int u = (t >= off) ? lds[t - off] : 0;
        __syncthreads();
        lds[t] += u;
        __syncthreads();
    }
    counts[k * NCHUNK + t] = lds[t] - v;   // exclusive within bucket
    if (t == NCHUNK - 1) btot[k] = lds[t];
}

__global__ __launch_bounds__(512) void k_scanB(const int* __restrict__ btot,
                                               int* __restrict__ bbase) {
    __shared__ int lds[512];
    const int t = threadIdx.x;
    int v = (t < NBUCKET) ? btot[t] : 0;
    lds[t] = v;
    __syncthreads();
    for (int off = 1; off < 512; off <<= 1) {
        int u = (t >= off) ? lds[t - off] : 0;
        __syncthreads();
        lds[t] += u;
        __syncthreads();
    }
    if (t < NBUCKET) bbase[t] = lds[t] - v;
    if (t == 511) bbase[NBUCKET] = lds[511];   // == N_EDGES
}

__global__ __launch_bounds__(256) void k_reorder(const int2* __restrict__ ei,
                                                 const int* __restrict__ counts,
                                                 const int* __restrict__ bbase,
                                                 int* __restrict__ pairs) {
    __shared__ int cur[NBUCKET];
    const int b = blockIdx.x;
    for (int i = threadIdx.x; i < NBUCKET; i += 256)
        cur[i] = bbase[i] + counts[i * NCHUNK + b];
    __syncthreads();
    const int beg = b * CE, end = min(N_EDGES, beg + CE);
    for (int e = beg + threadIdx.x; e < end; e += 256) {
        int2 v = ei[e];
        int k = v.y >> 8;
        int pos = atomicAdd(&cur[k], 1);      // LDS atomic only
        pairs[pos] = (v.x << 8) | (v.y & 255);
    }
}

__global__ __launch_bounds__(256) void k_csr(const int* __restrict__ pairs,
                                             const int* __restrict__ bbase,
                                             int* __restrict__ rowg,
                                             int* __restrict__ degg,
                                             int* __restrict__ sorted_src) {
    __shared__ int deg[256], scn[256], cur[256];
    const int k = blockIdx.x, t = threadIdx.x;
    const int n0 = k << 8;
    const int nn = min(256, N_NODES - n0);
    deg[t] = 0;
    __syncthreads();
    const int ebeg = bbase[k], eend = bbase[k + 1];
    for (int e = ebeg + t; e < eend; e += 256)
        atomicAdd(&deg[pairs[e] & 255], 1);
    __syncthreads();
    int v = (t < nn) ? deg[t] : 0;
    scn[t] = v;
    __syncthreads();
    for (int off = 1; off < 256; off <<= 1) {
        int u = (t >= off) ? scn[t - off] : 0;
        __syncthreads();
        scn[t] += u;
        __syncthreads();
    }
    int excl = scn[t] - v;
    if (t < nn) {
        int r = ebeg + excl + n0 + t;   // + self-loops of all preceding nodes
        rowg[n0 + t] = r;
        degg[n0 + t] = v + 1;
        sorted_src[r] = n0 + t;         // self-loop occupies slot 0
        cur[t] = r + 1;
    }
    __syncthreads();
    for (int e = ebeg + t; e < eend; e += 256) {
        int p = pairs[e];
        int pos = atomicAdd(&cur[p & 255], 1);   // LDS atomic only
        sorted_src[pos] = p >> 8;
    }
}

// ---- layer-1 aggregation (4 lanes/node, fp16 h) fused with mid-layer matmul ----
// No max-subtraction: scores are O(+-10) so exp(e) is fp32-safe, and
// exp(e)/sum == exp(e-m)/sum(exp(e-m)) identically.
// Cross-chunk software pipeline: next chunk's src indices prefetched (nt loads)
// while the current chunk's es/h gathers are in flight -> 1 round-trip/chunk.
__global__ __launch_bounds__(256) void k_agg1(
        const int* __restrict__ row, const int* __restrict__ deg,
        const int* __restrict__ sorted_src,
        const float* __restrict__ es, const float* __restrict__ ed,
        const _Float16* __restrict__ h1h, const float* __restrict__ b1,
        const float* __restrict__ W2, const float* __restrict__ a2s,
        const float* __restrict__ a2d,
        float* __restrict__ h2, float* __restrict__ e2s, float* __restrict__ e2d) {
    __shared__ float w2s[H1 * H2];
    __shared__ float a2ss[H2], a2ds[H2];
    if (threadIdx.x < H1 * H2) w2s[threadIdx.x] = W2[threadIdx.x];
    if (threadIdx.x < H2) { a2ss[threadIdx.x] = a2s[threadIdx.x]; a2ds[threadIdx.x] = a2d[threadIdx.x]; }
    __syncthreads();
    const int sub = threadIdx.x & 3;
    const int node = (blockIdx.x * 256 + threadIdx.x) >> 2;
    if (node >= N_NODES) return;
    const int beg = row[node];
    const int cnt = deg[node];            // >= 1 (self-loop)
    const int last = beg + cnt - 1;
    const float edv = ed[node];
    const half4v* h4 = (const half4v*)h1h;
    float4 acc = make_float4(0.f, 0.f, 0.f, 0.f);
    float s = 0.f;
    int cur[UA], nxt[UA];
    #pragma unroll
    for (int i = 0; i < UA; i++)
        cur[i] = __builtin_nontemporal_load(sorted_src + min(beg + i, last));
    for (int t0 = 0; t0 < cnt; t0 += UA) {
        float evs[UA];
        float4 hvs[UA];
        #pragma unroll
        for (int i = 0; i < UA; i++) {
            int sv = cur[i];
            evs[i] = es[sv];
            half4v hv = h4[(size_t)sv * 4 + sub];
            hvs[i] = make_float4((float)hv.x, (float)hv.y, (float)hv.z, (float)hv.w);
        }
        #pragma unroll
        for (int i = 0; i < UA; i++)
            nxt[i] = __builtin_nontemporal_load(sorted_src + min(beg + t0 + UA + i, last));
        #pragma unroll
        for (int i = 0; i < UA; i++) {
            if (t0 + i < cnt) {
                float e = evs[i] + edv;
                e = e > 0.f ? e : NEG * e;
                float p = __expf(e);
                s += p;
                acc.x += p * hvs[i].x;
                acc.y += p * hvs[i].y;
                acc.z += p * hvs[i].z;
                acc.w += p * hvs[i].w;
            }
        }
        #pragma unroll
        for (int i = 0; i < UA; i++) cur[i] = nxt[i];
    }
    const float inv = 1.f / s;
    const float4 b4 = ((const float4*)b1)[sub];
    float4 o;
    o.x = fmaxf(acc.x * inv + b4.x, 0.f);
    o.y = fmaxf(acc.y * inv + b4.y, 0.f);
    o.z = fmaxf(acc.z * inv + b4.z, 0.f);
    o.w = fmaxf(acc.w * inv + b4.w, 0.f);
    // fused mid: h2[node] = h1f @ W2 (16x8), h1f split 4 floats/lane
    float p2[H2];
    const float* wr = w2s + (sub * 4) * H2;
    #pragma unroll
    for (int i = 0; i < H2; i++)
        p2[i] = o.x * wr[i] + o.y * wr[H2 + i] + o.z * wr[2 * H2 + i] + o.w * wr[3 * H2 + i];
    #pragma unroll
    for (int i = 0; i < H2; i++) {
        p2[i] += __shfl_xor(p2[i], 1, 4);
        p2[i] += __shfl_xor(p2[i], 2, 4);
    }
    if (sub == 0) {
        float hs = 0.f, hd = 0.f;
        #pragma unroll
        for (int i = 0; i < H2; i++) { hs += p2[i] * a2ss[i]; hd += p2[i] * a2ds[i]; }
        e2s[node] = hs;
        e2d[node] = hd;
        ((float4*)h2)[(size_t)node * 2] = make_float4(p2[0], p2[1], p2[2], p2[3]);
    } else if (sub == 1) {
        ((float4*)h2)[(size_t)node * 2 + 1] = make_float4(p2[4], p2[5], p2[6], p2[7]);
    }
}

// ---- layer-2 aggregation (2 lanes/node, fp32 h2) fused with final head ----
__global__ __launch_bounds__(256) void k_agg2(
        const int* __restrict__ row, const int* __restrict__ deg,
        const int* __restrict__ sorted_src,
        const float* __restrict__ es, const float* __restrict__ ed,
        const float* __restrict__ h2, const float* __restrict__ b2,
        const float* __restrict__ Wf, const float* __restrict__ bf,
        float* __restrict__ out) {
    const int sub = threadIdx.x & 1;
    const int node = (blockIdx.x * 256 + threadIdx.x) >> 1;
    if (node >= N_NODES) return;
    const int beg = row[node];
    const int cnt = deg[node];
    const int last = beg + cnt - 1;
    const float edv = ed[node];
    const float4* h4 = (const float4*)h2;
    float4 acc = make_float4(0.f, 0.f, 0.f, 0.f);
    float s = 0.f;
    int cur[UA], nxt[UA];
    #pragma unroll
    for (int i = 0; i < UA; i++)
        cur[i] = __builtin_nontemporal_load(sorted_src + min(beg + i, last));
    for (int t0 = 0; t0 < cnt; t0 += UA) {
        float evs[UA];
        float4 hvs[UA];
        #pragma unroll
        for (int i = 0; i < UA; i++) {
            int sv = cur[i];
            evs[i] = es[sv];
            hvs[i] = h4[(size_t)sv * 2 + sub];
        }
        #pragma unroll
        for (int i = 0; i < UA; i++)
            nxt[i] = __builtin_nontemporal_load(sorted_src + min(beg + t0 + UA + i, last));
        #pragma unroll
        for (int i = 0; i < UA; i++) {
            if (t0 + i < cnt) {
                float e = evs[i] + edv;
                e = e > 0.f ? e : NEG * e;
                float p = __expf(e);
                s += p;
                acc.x += p * hvs[i].x;
                acc.y += p * hvs[i].y;
                acc.z += p * hvs[i].z;
                acc.w += p * hvs[i].w;
            }
        }
        #pragma unroll
        for (int i = 0; i < UA; i++) cur[i] = nxt[i];
    }
    const float inv = 1.f / s;
    const float4 b4 = ((const float4*)b2)[sub];
    const float4 w4 = ((const float4*)Wf)[sub];
    float r = fmaxf(acc.x * inv + b4.x, 0.f) * w4.x
            + fmaxf(acc.y * inv + b4.y, 0.f) * w4.y
            + fmaxf(acc.z * inv + b4.z, 0.f) * w4.z
            + fmaxf(acc.w * inv + b4.w, 0.f) * w4.w;
    r += __shfl_xor(r, 1, 2);
    if (sub == 0) out[node] = r + bf[0];
}

extern "C" void kernel_launch(void* const* d_in, const int* in_sizes, int n_in,
                              void* d_out, int out_size, void* d_ws, size_t ws_size,
                              hipStream_t stream) {
    const float* x    = (const float*)d_in[0];
    const int2*  ei   = (const int2*)d_in[1];   // int32 pairs [src,dst]
    const float* W1   = (const float*)d_in[2];
    const float* a1s  = (const float*)d_in[3];
    const float* a1d  = (const float*)d_in[4];
    const float* b1   = (const float*)d_in[5];
    const float* W2   = (const float*)d_in[6];
    const float* a2s  = (const float*)d_in[7];
    const float* a2d  = (const float*)d_in[8];
    const float* b2   = (const float*)d_in[9];
    const float* Wf   = (const float*)d_in[10];
    const float* bf   = (const float*)d_in[11];
    float* out = (float*)d_out;

    // workspace layout (pairs/counts die after k_csr; h2/e2s/e2d alias pairs)
    char* wp = (char*)d_ws;
    int* sorted_src = (int*)wp;   wp += sizeof(int) * (size_t)E_TOT;
    int* pairs      = (int*)wp;   wp += sizeof(int) * (size_t)N_EDGES;   // 12.8 MB
    int* counts     = (int*)wp;   wp += sizeof(int) * (size_t)NBUCKET * NCHUNK;
    int* btot       = (int*)wp;   wp += sizeof(int) * (NBUCKET + 1);
    int* bbase      = (int*)wp;   wp += sizeof(int) * (NBUCKET + 1);
    int* degg       = (int*)wp;   wp += sizeof(int) * N_NODES;
    int* rowg       = (int*)wp;   wp += sizeof(int) * N_NODES;
    _Float16* h1h = (_Float16*)wp; wp += sizeof(_Float16) * (size_t)N_NODES * H1;  // 3.2 MB, L2-resident
    float* e1s = (float*)wp;      wp += sizeof(float) * N_NODES;
    float* e1d = (float*)wp;      wp += sizeof(float) * N_NODES;
    // aliases into the dead pairs region (3.2 + 0.4 + 0.4 MB <= 12.8 MB)
    float* h2  = (float*)pairs;
    float* e2s = h2 + (size_t)N_NODES * H2;
    float* e2d = e2s + N_NODES;

    // CSR build (atomic-free w.r.t. global memory)
    k_count<<<NCHUNK, 256, 0, stream>>>(ei, counts);
    k_scanA<<<NBUCKET, 512, 0, stream>>>(counts, btot);
    k_scanB<<<1, 512, 0, stream>>>(btot, bbase);
    k_reorder<<<NCHUNK, 256, 0, stream>>>(ei, counts, bbase, pairs);
    k_csr<<<NBUCKET, 256, 0, stream>>>(pairs, bbase, rowg, degg, sorted_src);
    // layer 1 (+ fused mid-layer matmul)
    k1_xw<<<N_NODES / 16, 256, 0, stream>>>(x, W1, a1s, a1d, h1h, e1s, e1d);
    k_agg1<<<(N_NODES * 4 + 255) / 256, 256, 0, stream>>>(
        rowg, degg, sorted_src, e1s, e1d, h1h, b1, W2, a2s, a2d, h2, e2s, e2d);
    // layer 2 (+ fused head)
    k_agg2<<<(N_NODES * 2 + 255) / 256, 256, 0, stream>>>(
        rowg, degg, sorted_src, e2s, e2d, h2, b2, Wf, bf, out);
}

// Round 7
// 339.444 us; speedup vs baseline: 1.1223x; 1.1223x over previous
//
#include <hip/hip_runtime.h>
#include <math.h>

#define N_NODES 100000
#define N_EDGES 3200000
#define E_TOT   (N_EDGES + N_NODES)
#define F_IN    128
#define H1      16
#define H2      8
#define NEG     0.2f
#define NBUCKET ((N_NODES + 255) >> 8)             // 391 buckets of 256 nodes
#define NCHUNK  512
#define CE      ((N_EDGES + NCHUNK - 1) / NCHUNK)  // 6250 edges per chunk
#define UA      8                                  // gather batch depth

typedef _Float16 half4v __attribute__((ext_vector_type(4)));

// ---- kernel 1: h1(fp16) = x @ W1 ; e1s = h1·a1s ; e1d = h1·a1d ----
__global__ __launch_bounds__(256) void k1_xw(
        const float* __restrict__ x, const float* __restrict__ W1,
        const float* __restrict__ a1s, const float* __restrict__ a1d,
        _Float16* __restrict__ h1h, float* __restrict__ e1s, float* __restrict__ e1d) {
    __shared__ float w1s[F_IN * H1];     // 8 KB
    __shared__ float xs[16 * 132];       // padded stride 132 -> conflict-free
    __shared__ float a1ss[H1], a1ds[H1];
    const int tid = threadIdx.x;
    for (int i = tid; i < F_IN * H1; i += 256) w1s[i] = W1[i];
    if (tid < H1) { a1ss[tid] = a1s[tid]; a1ds[tid] = a1d[tid]; }
    const int rowbase = blockIdx.x * 16;
    #pragma unroll
    for (int i = 0; i < 2; i++) {
        int q = tid + i * 256;
        int r = q >> 5, c = q & 31;
        float4 v = *(const float4*)(x + (size_t)(rowbase + r) * F_IN + c * 4);
        *(float4*)(xs + r * 132 + c * 4) = v;
    }
    __syncthreads();
    const int g = tid >> 4, j = tid & 15;
    const float* xrow = xs + g * 132;
    float acc = 0.f;
    #pragma unroll 8
    for (int k = 0; k < F_IN; k++) acc += xrow[k] * w1s[k * H1 + j];
    const int row = rowbase + g;
    h1h[(size_t)row * H1 + j] = (_Float16)acc;
    float ps = acc * a1ss[j];
    float pd = acc * a1ds[j];
    #pragma unroll
    for (int m = 8; m >= 1; m >>= 1) {
        ps += __shfl_xor(ps, m, 16);
        pd += __shfl_xor(pd, m, 16);
    }
    if (j == 0) { e1s[row] = ps; e1d[row] = pd; }
}

// ---- counting-sort CSR build (no global atomics) ----

__global__ __launch_bounds__(256) void k_count(const int2* __restrict__ ei,
                                               int* __restrict__ counts) {
    __shared__ int hist[NBUCKET];
    for (int i = threadIdx.x; i < NBUCKET; i += 256) hist[i] = 0;
    __syncthreads();
    const int b = blockIdx.x;
    const int beg = b * CE, end = min(N_EDGES, beg + CE);
    for (int e = beg + threadIdx.x; e < end; e += 256)
        atomicAdd(&hist[ei[e].y >> 8], 1);
    __syncthreads();
    for (int i = threadIdx.x; i < NBUCKET; i += 256)
        counts[i * NCHUNK + b] = hist[i];
}

__global__ __launch_bounds__(512) void k_scanA(int* __restrict__ counts,
                                               int* __restrict__ btot) {
    __shared__ int lds[NCHUNK];
    const int k = blockIdx.x, t = threadIdx.x;
    int v = counts[k * NCHUNK + t];
    lds[t] = v;
    __syncthreads();
    for (int off = 1; off < NCHUNK; off <<= 1) {
        int u = (t >= off) ? lds[t - off] : 0;
        __syncthreads();
        lds[t] += u;
        __syncthreads();
    }
    counts[k * NCHUNK + t] = lds[t] - v;   // exclusive within bucket
    if (t == NCHUNK - 1) btot[k] = lds[t];
}

__global__ __launch_bounds__(512) void k_scanB(const int* __restrict__ btot,
                                               int* __restrict__ bbase) {
    __shared__ int lds[512];
    const int t = threadIdx.x;
    int v = (t < NBUCKET) ? btot[t] : 0;
    lds[t] = v;
    __syncthreads();
    for (int off = 1; off < 512; off <<= 1) {
        int u = (t >= off) ? lds[t - off] : 0;
        __syncthreads();
        lds[t] += u;
        __syncthreads();
    }
    if (t < NBUCKET) bbase[t] = lds[t] - v;
    if (t == 511) bbase[NBUCKET] = lds[511];   // == N_EDGES
}

__global__ __launch_bounds__(256) void k_reorder(const int2* __restrict__ ei,
                                                 const int* __restrict__ counts,
                                                 const int* __restrict__ bbase,
                                                 int* __restrict__ pairs) {
    __shared__ int cur[NBUCKET];
    const int b = blockIdx.x;
    for (int i = threadIdx.x; i < NBUCKET; i += 256)
        cur[i] = bbase[i] + counts[i * NCHUNK + b];
    __syncthreads();
    const int beg = b * CE, end = min(N_EDGES, beg + CE);
    for (int e = beg + threadIdx.x; e < end; e += 256) {
        int2 v = ei[e];
        int k = v.y >> 8;
        int pos = atomicAdd(&cur[k], 1);      // LDS atomic only
        pairs[pos] = (v.x << 8) | (v.y & 255);
    }
}

// phase D: fine CSR in LDS; ALSO computes per-edge softmax weight
// w = exp(leaky(e1s[src]+e1d[dst])) and stores it fp16 at the sorted position.
// (No max-subtraction: scores are O(+-8) => exp safe in fp32/fp16 range, and
//  exp(e)/sum(exp(e)) == softmax identically.)
__global__ __launch_bounds__(256) void k_csr(const int* __restrict__ pairs,
                                             const int* __restrict__ bbase,
                                             const float* __restrict__ e1s,
                                             const float* __restrict__ e1d,
                                             int* __restrict__ rowg,
                                             int* __restrict__ degg,
                                             int* __restrict__ sorted_src,
                                             _Float16* __restrict__ w1h) {
    __shared__ int deg[256], scn[256], cur[256];
    __shared__ float e1dl[256];
    const int k = blockIdx.x, t = threadIdx.x;
    const int n0 = k << 8;
    const int nn = min(256, N_NODES - n0);
    deg[t] = 0;
    if (t < nn) e1dl[t] = e1d[n0 + t];
    __syncthreads();
    const int ebeg = bbase[k], eend = bbase[k + 1];
    for (int e = ebeg + t; e < eend; e += 256)
        atomicAdd(&deg[pairs[e] & 255], 1);
    __syncthreads();
    int v = (t < nn) ? deg[t] : 0;
    scn[t] = v;
    __syncthreads();
    for (int off = 1; off < 256; off <<= 1) {
        int u = (t >= off) ? scn[t - off] : 0;
        __syncthreads();
        scn[t] += u;
        __syncthreads();
    }
    int excl = scn[t] - v;
    if (t < nn) {
        int r = ebeg + excl + n0 + t;   // + self-loops of all preceding nodes
        rowg[n0 + t] = r;
        degg[n0 + t] = v + 1;
        sorted_src[r] = n0 + t;         // self-loop occupies slot 0
        float sc = e1s[n0 + t] + e1dl[t];
        sc = sc > 0.f ? sc : NEG * sc;
        w1h[r] = (_Float16)__expf(sc);
        cur[t] = r + 1;
    }
    __syncthreads();
    for (int e = ebeg + t; e < eend; e += 256) {
        int p = pairs[e];
        int dl = p & 255;
        int src = p >> 8;
        int pos = atomicAdd(&cur[dl], 1);        // LDS atomic only
        float sc = e1s[src] + e1dl[dl];
        sc = sc > 0.f ? sc : NEG * sc;
        sorted_src[pos] = src;
        w1h[pos] = (_Float16)__expf(sc);
    }
}

// ---- layer-1 aggregation (4 lanes/node, fp16 h, precomputed fp16 weights)
//      fused with mid-layer matmul h2 = relu(agg)@W2 and layer-2 scores ----
__global__ __launch_bounds__(256) void k_agg1(
        const int* __restrict__ row, const int* __restrict__ deg,
        const int* __restrict__ sorted_src, const _Float16* __restrict__ w1h,
        const _Float16* __restrict__ h1h, const float* __restrict__ b1,
        const float* __restrict__ W2, const float* __restrict__ a2s,
        const float* __restrict__ a2d,
        float* __restrict__ h2, float* __restrict__ e2s, float* __restrict__ e2d) {
    __shared__ float w2s[H1 * H2];
    __shared__ float a2ss[H2], a2ds[H2];
    if (threadIdx.x < H1 * H2) w2s[threadIdx.x] = W2[threadIdx.x];
    if (threadIdx.x < H2) { a2ss[threadIdx.x] = a2s[threadIdx.x]; a2ds[threadIdx.x] = a2d[threadIdx.x]; }
    __syncthreads();
    const int sub = threadIdx.x & 3;
    const int node = (blockIdx.x * 256 + threadIdx.x) >> 2;
    if (node >= N_NODES) return;
    const int beg = row[node];
    const int cnt = deg[node];            // >= 1 (self-loop)
    const int last = beg + cnt - 1;
    const half4v* h4 = (const half4v*)h1h;
    float4 acc = make_float4(0.f, 0.f, 0.f, 0.f);
    float s = 0.f;
    for (int t0 = 0; t0 < cnt; t0 += UA) {
        int idx[UA];
        float ws[UA];
        float4 hvs[UA];
        #pragma unroll
        for (int i = 0; i < UA; i++) {           // coalesced stream loads
            int q = min(beg + t0 + i, last);
            idx[i] = sorted_src[q];
            ws[i] = (t0 + i < cnt) ? (float)w1h[q] : 0.f;   // 0-pad tail: branch-free fma phase
        }
        #pragma unroll
        for (int i = 0; i < UA; i++) {           // the only gather stream
            half4v hv = h4[(size_t)idx[i] * 4 + sub];
            hvs[i] = make_float4((float)hv.x, (float)hv.y, (float)hv.z, (float)hv.w);
        }
        #pragma unroll
        for (int i = 0; i < UA; i++) {
            s += ws[i];
            acc.x += ws[i] * hvs[i].x;
            acc.y += ws[i] * hvs[i].y;
            acc.z += ws[i] * hvs[i].z;
            acc.w += ws[i] * hvs[i].w;
        }
    }
    const float inv = 1.f / s;
    const float4 b4 = ((const float4*)b1)[sub];
    float4 o;
    o.x = fmaxf(acc.x * inv + b4.x, 0.f);
    o.y = fmaxf(acc.y * inv + b4.y, 0.f);
    o.z = fmaxf(acc.z * inv + b4.z, 0.f);
    o.w = fmaxf(acc.w * inv + b4.w, 0.f);
    // fused mid: h2[node] = h1f @ W2 (16x8), h1f split 4 floats/lane
    float p2[H2];
    const float* wr = w2s + (sub * 4) * H2;
    #pragma unroll
    for (int i = 0; i < H2; i++)
        p2[i] = o.x * wr[i] + o.y * wr[H2 + i] + o.z * wr[2 * H2 + i] + o.w * wr[3 * H2 + i];
    #pragma unroll
    for (int i = 0; i < H2; i++) {
        p2[i] += __shfl_xor(p2[i], 1, 4);
        p2[i] += __shfl_xor(p2[i], 2, 4);
    }
    if (sub == 0) {
        float hs = 0.f, hd = 0.f;
        #pragma unroll
        for (int i = 0; i < H2; i++) { hs += p2[i] * a2ss[i]; hd += p2[i] * a2ds[i]; }
        e2s[node] = hs;
        e2d[node] = hd;
        ((float4*)h2)[(size_t)node * 2] = make_float4(p2[0], p2[1], p2[2], p2[3]);
    } else if (sub == 1) {
        ((float4*)h2)[(size_t)node * 2 + 1] = make_float4(p2[4], p2[5], p2[6], p2[7]);
    }
}

// ---- layer-2 aggregation (2 lanes/node, fp32 h2) fused with final head ----
__global__ __launch_bounds__(256) void k_agg2(
        const int* __restrict__ row, const int* __restrict__ deg,
        const int* __restrict__ sorted_src,
        const float* __restrict__ es, const float* __restrict__ ed,
        const float* __restrict__ h2, const float* __restrict__ b2,
        const float* __restrict__ Wf, const float* __restrict__ bf,
        float* __restrict__ out) {
    const int sub = threadIdx.x & 1;
    const int node = (blockIdx.x * 256 + threadIdx.x) >> 1;
    if (node >= N_NODES) return;
    const int beg = row[node];
    const int cnt = deg[node];
    const int last = beg + cnt - 1;
    const float edv = ed[node];
    const float4* h4 = (const float4*)h2;
    float4 acc = make_float4(0.f, 0.f, 0.f, 0.f);
    float s = 0.f;
    for (int t0 = 0; t0 < cnt; t0 += UA) {
        int idx[UA];
        float evs[UA];
        float4 hvs[UA];
        #pragma unroll
        for (int i = 0; i < UA; i++)
            idx[i] = sorted_src[min(beg + t0 + i, last)];
        #pragma unroll
        for (int i = 0; i < UA; i++) {
            evs[i] = es[idx[i]];
            hvs[i] = h4[(size_t)idx[i] * 2 + sub];
        }
        #pragma unroll
        for (int i = 0; i < UA; i++) {
            if (t0 + i < cnt) {
                float e = evs[i] + edv;
                e = e > 0.f ? e : NEG * e;
                float p = __expf(e);
                s += p;
                acc.x += p * hvs[i].x;
                acc.y += p * hvs[i].y;
                acc.z += p * hvs[i].z;
                acc.w += p * hvs[i].w;
            }
        }
    }
    const float inv = 1.f / s;
    const float4 b4 = ((const float4*)b2)[sub];
    const float4 w4 = ((const float4*)Wf)[sub];
    float r = fmaxf(acc.x * inv + b4.x, 0.f) * w4.x
            + fmaxf(acc.y * inv + b4.y, 0.f) * w4.y
            + fmaxf(acc.z * inv + b4.z, 0.f) * w4.z
            + fmaxf(acc.w * inv + b4.w, 0.f) * w4.w;
    r += __shfl_xor(r, 1, 2);
    if (sub == 0) out[node] = r + bf[0];
}

extern "C" void kernel_launch(void* const* d_in, const int* in_sizes, int n_in,
                              void* d_out, int out_size, void* d_ws, size_t ws_size,
                              hipStream_t stream) {
    const float* x    = (const float*)d_in[0];
    const int2*  ei   = (const int2*)d_in[1];   // int32 pairs [src,dst]
    const float* W1   = (const float*)d_in[2];
    const float* a1s  = (const float*)d_in[3];
    const float* a1d  = (const float*)d_in[4];
    const float* b1   = (const float*)d_in[5];
    const float* W2   = (const float*)d_in[6];
    const float* a2s  = (const float*)d_in[7];
    const float* a2d  = (const float*)d_in[8];
    const float* b2   = (const float*)d_in[9];
    const float* Wf   = (const float*)d_in[10];
    const float* bf   = (const float*)d_in[11];
    float* out = (float*)d_out;

    // workspace layout (pairs dies after k_csr; h2/e2s/e2d alias pairs)
    char* wp = (char*)d_ws;
    int* sorted_src = (int*)wp;     wp += sizeof(int) * (size_t)E_TOT;       // 13.2 MB
    _Float16* w1h  = (_Float16*)wp; wp += sizeof(_Float16) * (size_t)E_TOT;  // 6.6 MB
    int* pairs      = (int*)wp;     wp += sizeof(int) * (size_t)N_EDGES;     // 12.8 MB
    int* counts     = (int*)wp;     wp += sizeof(int) * (size_t)NBUCKET * NCHUNK;
    int* btot       = (int*)wp;     wp += sizeof(int) * (NBUCKET + 1);
    int* bbase      = (int*)wp;     wp += sizeof(int) * (NBUCKET + 1);
    int* degg       = (int*)wp;     wp += sizeof(int) * N_NODES;
    int* rowg       = (int*)wp;     wp += sizeof(int) * N_NODES;
    _Float16* h1h = (_Float16*)wp;  wp += sizeof(_Float16) * (size_t)N_NODES * H1;  // 3.2 MB
    float* e1s = (float*)wp;        wp += sizeof(float) * N_NODES;
    float* e1d = (float*)wp;        wp += sizeof(float) * N_NODES;
    // aliases into the dead pairs region (3.2 + 0.4 + 0.4 MB <= 12.8 MB)
    float* h2  = (float*)pairs;
    float* e2s = h2 + (size_t)N_NODES * H2;
    float* e2d = e2s + N_NODES;

    // layer-1 dense part first (k_csr consumes e1s/e1d)
    k1_xw<<<N_NODES / 16, 256, 0, stream>>>(x, W1, a1s, a1d, h1h, e1s, e1d);
    // CSR build (atomic-free w.r.t. global memory); k_csr also emits edge weights
    k_count<<<NCHUNK, 256, 0, stream>>>(ei, counts);
    k_scanA<<<NBUCKET, 512, 0, stream>>>(counts, btot);
    k_scanB<<<1, 512, 0, stream>>>(btot, bbase);
    k_reorder<<<NCHUNK, 256, 0, stream>>>(ei, counts, bbase, pairs);
    k_csr<<<NBUCKET, 256, 0, stream>>>(pairs, bbase, e1s, e1d, rowg, degg, sorted_src, w1h);
    // layer 1 aggregation (+ fused mid-layer matmul)
    k_agg1<<<(N_NODES * 4 + 255) / 256, 256, 0, stream>>>(
        rowg, degg, sorted_src, w1h, h1h, b1, W2, a2s, a2d, h2, e2s, e2d);
    // layer 2 aggregation (+ fused head)
    k_agg2<<<(N_NODES * 2 + 255) / 256, 256, 0, stream>>>(
        rowg, degg, sorted_src, e2s, e2d, h2, b2, Wf, bf, out);
}

// Round 8
// 301.018 us; speedup vs baseline: 1.2656x; 1.1277x over previous
//
#include <hip/hip_runtime.h>
#include <math.h>

#define N_NODES 100000
#define N_EDGES 3200000
#define E_TOT   (N_EDGES + N_NODES)
#define F_IN    128
#define H1      16
#define H2      8
#define NEG     0.2f
#define NBUCKET ((N_NODES + 255) >> 8)             // 391 buckets of 256 nodes
#define NCHUNK  512
#define CE      ((N_EDGES + NCHUNK - 1) / NCHUNK)  // 6250 edges per chunk
#define UA      8                                  // gather batch depth

typedef _Float16 half4v __attribute__((ext_vector_type(4)));
typedef int int4a __attribute__((ext_vector_type(4), aligned(4)));  // 4B-aligned int4

__device__ inline int clampu(int v) {              // poison/tail-safe index clamp
    return (int)min((unsigned)v, (unsigned)(N_NODES - 1));
}

// ---- kernel 1: h1(fp16) = x @ W1 ; e1s = h1·a1s ; e1d = h1·a1d ----
__global__ __launch_bounds__(256) void k1_xw(
        const float* __restrict__ x, const float* __restrict__ W1,
        const float* __restrict__ a1s, const float* __restrict__ a1d,
        _Float16* __restrict__ h1h, float* __restrict__ e1s, float* __restrict__ e1d) {
    __shared__ float w1s[F_IN * H1];     // 8 KB
    __shared__ float xs[16 * 132];       // padded stride 132 -> conflict-free
    __shared__ float a1ss[H1], a1ds[H1];
    const int tid = threadIdx.x;
    for (int i = tid; i < F_IN * H1; i += 256) w1s[i] = W1[i];
    if (tid < H1) { a1ss[tid] = a1s[tid]; a1ds[tid] = a1d[tid]; }
    const int rowbase = blockIdx.x * 16;
    #pragma unroll
    for (int i = 0; i < 2; i++) {
        int q = tid + i * 256;
        int r = q >> 5, c = q & 31;
        float4 v = *(const float4*)(x + (size_t)(rowbase + r) * F_IN + c * 4);
        *(float4*)(xs + r * 132 + c * 4) = v;
    }
    __syncthreads();
    const int g = tid >> 4, j = tid & 15;
    const float* xrow = xs + g * 132;
    float acc = 0.f;
    #pragma unroll 8
    for (int k = 0; k < F_IN; k++) acc += xrow[k] * w1s[k * H1 + j];
    const int row = rowbase + g;
    h1h[(size_t)row * H1 + j] = (_Float16)acc;
    float ps = acc * a1ss[j];
    float pd = acc * a1ds[j];
    #pragma unroll
    for (int m = 8; m >= 1; m >>= 1) {
        ps += __shfl_xor(ps, m, 16);
        pd += __shfl_xor(pd, m, 16);
    }
    if (j == 0) { e1s[row] = ps; e1d[row] = pd; }
}

// ---- counting-sort CSR build (no global atomics) ----

__global__ __launch_bounds__(256) void k_count(const int2* __restrict__ ei,
                                               int* __restrict__ counts) {
    __shared__ int hist[NBUCKET];
    for (int i = threadIdx.x; i < NBUCKET; i += 256) hist[i] = 0;
    __syncthreads();
    const int b = blockIdx.x;
    const int beg = b * CE, end = min(N_EDGES, beg + CE);
    for (int e = beg + threadIdx.x; e < end; e += 256)
        atomicAdd(&hist[ei[e].y >> 8], 1);
    __syncthreads();
    for (int i = threadIdx.x; i < NBUCKET; i += 256)
        counts[i * NCHUNK + b] = hist[i];
}

__global__ __launch_bounds__(512) void k_scanA(int* __restrict__ counts,
                                               int* __restrict__ btot) {
    __shared__ int lds[NCHUNK];
    const int k = blockIdx.x, t = threadIdx.x;
    int v = counts[k * NCHUNK + t];
    lds[t] = v;
    __syncthreads();
    for (int off = 1; off < NCHUNK; off <<= 1) {
        int u = (t >= off) ? lds[t - off] : 0;
        __syncthreads();
        lds[t] += u;
        __syncthreads();
    }
    counts[k * NCHUNK + t] = lds[t] - v;   // exclusive within bucket
    if (t == NCHUNK - 1) btot[k] = lds[t];
}

__global__ __launch_bounds__(512) void k_scanB(const int* __restrict__ btot,
                                               int* __restrict__ bbase) {
    __shared__ int lds[512];
    const int t = threadIdx.x;
    int v = (t < NBUCKET) ? btot[t] : 0;
    lds[t] = v;
    __syncthreads();
    for (int off = 1; off < 512; off <<= 1) {
        int u = (t >= off) ? lds[t - off] : 0;
        __syncthreads();
        lds[t] += u;
        __syncthreads();
    }
    if (t < NBUCKET) bbase[t] = lds[t] - v;
    if (t == 511) bbase[NBUCKET] = lds[511];   // == N_EDGES
}

__global__ __launch_bounds__(256) void k_reorder(const int2* __restrict__ ei,
                                                 const int* __restrict__ counts,
                                                 const int* __restrict__ bbase,
                                                 int* __restrict__ pairs) {
    __shared__ int cur[NBUCKET];
    const int b = blockIdx.x;
    for (int i = threadIdx.x; i < NBUCKET; i += 256)
        cur[i] = bbase[i] + counts[i * NCHUNK + b];
    __syncthreads();
    const int beg = b * CE, end = min(N_EDGES, beg + CE);
    for (int e = beg + threadIdx.x; e < end; e += 256) {
        int2 v = ei[e];
        int k = v.y >> 8;
        int pos = atomicAdd(&cur[k], 1);      // LDS atomic only
        pairs[pos] = (v.x << 8) | (v.y & 255);
    }
}

__global__ __launch_bounds__(256) void k_csr(const int* __restrict__ pairs,
                                             const int* __restrict__ bbase,
                                             int* __restrict__ rowg,
                                             int* __restrict__ degg,
                                             int* __restrict__ sorted_src) {
    __shared__ int deg[256], scn[256], cur[256];
    const int k = blockIdx.x, t = threadIdx.x;
    const int n0 = k << 8;
    const int nn = min(256, N_NODES - n0);
    deg[t] = 0;
    __syncthreads();
    const int ebeg = bbase[k], eend = bbase[k + 1];
    for (int e = ebeg + t; e < eend; e += 256)
        atomicAdd(&deg[pairs[e] & 255], 1);
    __syncthreads();
    int v = (t < nn) ? deg[t] : 0;
    scn[t] = v;
    __syncthreads();
    for (int off = 1; off < 256; off <<= 1) {
        int u = (t >= off) ? scn[t - off] : 0;
        __syncthreads();
        scn[t] += u;
        __syncthreads();
    }
    int excl = scn[t] - v;
    if (t < nn) {
        int r = ebeg + excl + n0 + t;   // + self-loops of all preceding nodes
        rowg[n0 + t] = r;
        degg[n0 + t] = v + 1;
        sorted_src[r] = n0 + t;         // self-loop occupies slot 0
        cur[t] = r + 1;
    }
    __syncthreads();
    for (int e = ebeg + t; e < eend; e += 256) {
        int p = pairs[e];
        int pos = atomicAdd(&cur[p & 255], 1);   // LDS atomic only
        sorted_src[pos] = p >> 8;
    }
}

// ---- layer-1 aggregation (4 lanes/node, fp16 h) fused with mid matmul ----
// No max-subtraction: scores are O(+-10) so exp(e) is fp32-safe, and
// exp(e)/sum == exp(e-m)/sum(exp(e-m)) identically.
// sorted_src read via WIDE nt loads: one line-touch per lane, no L2 retention
// -> the 3.2 MB h1h table stays resident in each XCD's 4 MB L2.
__global__ __launch_bounds__(256) void k_agg1(
        const int* __restrict__ row, const int* __restrict__ deg,
        const int* __restrict__ sorted_src,
        const float* __restrict__ es, const float* __restrict__ ed,
        const _Float16* __restrict__ h1h, const float* __restrict__ b1,
        const float* __restrict__ W2, const float* __restrict__ a2s,
        const float* __restrict__ a2d,
        float* __restrict__ h2, float* __restrict__ e2s, float* __restrict__ e2d) {
    __shared__ float w2s[H1 * H2];
    __shared__ float a2ss[H2], a2ds[H2];
    if (threadIdx.x < H1 * H2) w2s[threadIdx.x] = W2[threadIdx.x];
    if (threadIdx.x < H2) { a2ss[threadIdx.x] = a2s[threadIdx.x]; a2ds[threadIdx.x] = a2d[threadIdx.x]; }
    __syncthreads();
    const int sub = threadIdx.x & 3;
    const int node = (blockIdx.x * 256 + threadIdx.x) >> 2;
    if (node >= N_NODES) return;
    const int beg = row[node];
    const int cnt = deg[node];            // >= 1 (self-loop)
    const float edv = ed[node];
    const half4v* h4 = (const half4v*)h1h;
    float4 acc = make_float4(0.f, 0.f, 0.f, 0.f);
    float s = 0.f;
    for (int t0 = 0; t0 < cnt; t0 += UA) {
        int4a i0 = __builtin_nontemporal_load((const int4a*)(sorted_src + beg + t0));
        int4a i1 = __builtin_nontemporal_load((const int4a*)(sorted_src + beg + t0 + 4));
        int idx[UA] = {clampu(i0.x), clampu(i0.y), clampu(i0.z), clampu(i0.w),
                       clampu(i1.x), clampu(i1.y), clampu(i1.z), clampu(i1.w)};
        float evs[UA];
        float4 hvs[UA];
        #pragma unroll
        for (int i = 0; i < UA; i++) {
            evs[i] = es[idx[i]];
            half4v hv = h4[(size_t)idx[i] * 4 + sub];
            hvs[i] = make_float4((float)hv.x, (float)hv.y, (float)hv.z, (float)hv.w);
        }
        #pragma unroll
        for (int i = 0; i < UA; i++) {
            if (t0 + i < cnt) {
                float e = evs[i] + edv;
                e = e > 0.f ? e : NEG * e;
                float p = __expf(e);
                s += p;
                acc.x += p * hvs[i].x;
                acc.y += p * hvs[i].y;
                acc.z += p * hvs[i].z;
                acc.w += p * hvs[i].w;
            }
        }
    }
    const float inv = 1.f / s;
    const float4 b4 = ((const float4*)b1)[sub];
    float4 o;
    o.x = fmaxf(acc.x * inv + b4.x, 0.f);
    o.y = fmaxf(acc.y * inv + b4.y, 0.f);
    o.z = fmaxf(acc.z * inv + b4.z, 0.f);
    o.w = fmaxf(acc.w * inv + b4.w, 0.f);
    // fused mid: h2[node] = h1f @ W2 (16x8), h1f split 4 floats/lane
    float p2[H2];
    const float* wr = w2s + (sub * 4) * H2;
    #pragma unroll
    for (int i = 0; i < H2; i++)
        p2[i] = o.x * wr[i] + o.y * wr[H2 + i] + o.z * wr[2 * H2 + i] + o.w * wr[3 * H2 + i];
    #pragma unroll
    for (int i = 0; i < H2; i++) {
        p2[i] += __shfl_xor(p2[i], 1, 4);
        p2[i] += __shfl_xor(p2[i], 2, 4);
    }
    if (sub == 0) {
        float hs = 0.f, hd = 0.f;
        #pragma unroll
        for (int i = 0; i < H2; i++) { hs += p2[i] * a2ss[i]; hd += p2[i] * a2ds[i]; }
        e2s[node] = hs;
        e2d[node] = hd;
        ((float4*)h2)[(size_t)node * 2] = make_float4(p2[0], p2[1], p2[2], p2[3]);
    } else if (sub == 1) {
        ((float4*)h2)[(size_t)node * 2 + 1] = make_float4(p2[4], p2[5], p2[6], p2[7]);
    }
}

// ---- layer-2 aggregation (2 lanes/node, fp32 h2) fused with final head ----
__global__ __launch_bounds__(256) void k_agg2(
        const int* __restrict__ row, const int* __restrict__ deg,
        const int* __restrict__ sorted_src,
        const float* __restrict__ es, const float* __restrict__ ed,
        const float* __restrict__ h2, const float* __restrict__ b2,
        const float* __restrict__ Wf, const float* __restrict__ bf,
        float* __restrict__ out) {
    const int sub = threadIdx.x & 1;
    const int node = (blockIdx.x * 256 + threadIdx.x) >> 1;
    if (node >= N_NODES) return;
    const int beg = row[node];
    const int cnt = deg[node];
    const float edv = ed[node];
    const float4* h4 = (const float4*)h2;
    float4 acc = make_float4(0.f, 0.f, 0.f, 0.f);
    float s = 0.f;
    for (int t0 = 0; t0 < cnt; t0 += UA) {
        int4a i0 = __builtin_nontemporal_load((const int4a*)(sorted_src + beg + t0));
        int4a i1 = __builtin_nontemporal_load((const int4a*)(sorted_src + beg + t0 + 4));
        int idx[UA] = {clampu(i0.x), clampu(i0.y), clampu(i0.z), clampu(i0.w),
                       clampu(i1.x), clampu(i1.y), clampu(i1.z), clampu(i1.w)};
        float evs[UA];
        float4 hvs[UA];
        #pragma unroll
        for (int i = 0; i < UA; i++) {
            evs[i] = es[idx[i]];
            hvs[i] = h4[(size_t)idx[i] * 2 + sub];
        }
        #pragma unroll
        for (int i = 0; i < UA; i++) {
            if (t0 + i < cnt) {
                float e = evs[i] + edv;
                e = e > 0.f ? e : NEG * e;
                float p = __expf(e);
                s += p;
                acc.x += p * hvs[i].x;
                acc.y += p * hvs[i].y;
                acc.z += p * hvs[i].z;
                acc.w += p * hvs[i].w;
            }
        }
    }
    const float inv = 1.f / s;
    const float4 b4 = ((const float4*)b2)[sub];
    const float4 w4 = ((const float4*)Wf)[sub];
    float r = fmaxf(acc.x * inv + b4.x, 0.f) * w4.x
            + fmaxf(acc.y * inv + b4.y, 0.f) * w4.y
            + fmaxf(acc.z * inv + b4.z, 0.f) * w4.z
            + fmaxf(acc.w * inv + b4.w, 0.f) * w4.w;
    r += __shfl_xor(r, 1, 2);
    if (sub == 0) out[node] = r + bf[0];
}

extern "C" void kernel_launch(void* const* d_in, const int* in_sizes, int n_in,
                              void* d_out, int out_size, void* d_ws, size_t ws_size,
                              hipStream_t stream) {
    const float* x    = (const float*)d_in[0];
    const int2*  ei   = (const int2*)d_in[1];   // int32 pairs [src,dst]
    const float* W1   = (const float*)d_in[2];
    const float* a1s  = (const float*)d_in[3];
    const float* a1d  = (const float*)d_in[4];
    const float* b1   = (const float*)d_in[5];
    const float* W2   = (const float*)d_in[6];
    const float* a2s  = (const float*)d_in[7];
    const float* a2d  = (const float*)d_in[8];
    const float* b2   = (const float*)d_in[9];
    const float* Wf   = (const float*)d_in[10];
    const float* bf   = (const float*)d_in[11];
    float* out = (float*)d_out;

    // workspace layout (pairs/counts die after k_csr; h2/e2s/e2d alias pairs)
    char* wp = (char*)d_ws;
    int* sorted_src = (int*)wp;   wp += sizeof(int) * ((size_t)E_TOT + 8);  // +8 pad for int4 tail reads
    int* pairs      = (int*)wp;   wp += sizeof(int) * (size_t)N_EDGES;      // 12.8 MB
    int* counts     = (int*)wp;   wp += sizeof(int) * (size_t)NBUCKET * NCHUNK;
    int* btot       = (int*)wp;   wp += sizeof(int) * (NBUCKET + 1);
    int* bbase      = (int*)wp;   wp += sizeof(int) * (NBUCKET + 1);
    int* degg       = (int*)wp;   wp += sizeof(int) * N_NODES;
    int* rowg       = (int*)wp;   wp += sizeof(int) * N_NODES;
    _Float16* h1h = (_Float16*)wp; wp += sizeof(_Float16) * (size_t)N_NODES * H1;  // 3.2 MB, L2-resident
    float* e1s = (float*)wp;      wp += sizeof(float) * N_NODES;
    float* e1d = (float*)wp;      wp += sizeof(float) * N_NODES;
    // aliases into the dead pairs region (3.2 + 0.4 + 0.4 MB <= 12.8 MB)
    float* h2  = (float*)pairs;
    float* e2s = h2 + (size_t)N_NODES * H2;
    float* e2d = e2s + N_NODES;

    // CSR build first (streams its ~45 MB through L2 BEFORE h1h is produced)
    k_count<<<NCHUNK, 256, 0, stream>>>(ei, counts);
    k_scanA<<<NBUCKET, 512, 0, stream>>>(counts, btot);
    k_scanB<<<1, 512, 0, stream>>>(btot, bbase);
    k_reorder<<<NCHUNK, 256, 0, stream>>>(ei, counts, bbase, pairs);
    k_csr<<<NBUCKET, 256, 0, stream>>>(pairs, bbase, rowg, degg, sorted_src);
    // layer-1 dense part right before agg1 -> h1h is L2/LLC-warm
    k1_xw<<<N_NODES / 16, 256, 0, stream>>>(x, W1, a1s, a1d, h1h, e1s, e1d);
    // layer 1 aggregation (+ fused mid-layer matmul + layer-2 scores)
    k_agg1<<<(N_NODES * 4 + 255) / 256, 256, 0, stream>>>(
        rowg, degg, sorted_src, e1s, e1d, h1h, b1, W2, a2s, a2d, h2, e2s, e2d);
    // layer 2 aggregation (+ fused head)
    k_agg2<<<(N_NODES * 2 + 255) / 256, 256, 0, stream>>>(
        rowg, degg, sorted_src, e2s, e2d, h2, b2, Wf, bf, out);
}